// Round 13
// baseline (201.030 us; speedup 1.0000x reference)
//
#include <hip/hip_runtime.h>
#include <hip/hip_bf16.h>
#include <stdint.h>

// MHSA: B=2, T=2048, C=1024, H=16, d=64. fp32 in/out, bf16 MFMA, fp32 accum.
// r11 (this session): K1 -> 8-phase 256x256 ring-scheduled GEMM (gemm8p).
//   Evidence: K1 ~43us @ ~23% MfmaUtil in the r15 build; 2-barrier structure
//   self-limits (single-buf 20% MfmaUtil; dbuf+drain regressed r10; counted
//   vmcnt at distance-1 == r10). 8-phase counted-vmcnt is the documented
//   +28-41% lever (T3+T4), 256 tile only (128+8ph measured null).
//   Schedule (desk-verified twice; r12 ledger: at tile-t q3 outstanding =
//   B(t+1)4+A(t+1)4+B(t+2)4=12, vmcnt(4) drains exactly B(t+1)+A(t+1) = the
//   next tile's q0 reads; all slot reuses end-barrier-separated).
//   setprio(1) around MFMA (T5, +21-25% verified ON 8-phase structures).
//   attn/pre/post/K3/small-ws: byte-identical to the 185.3us-verified r15
//   (setprio on attn dropped: r11 measured null-to-harmful, matches m190).

typedef __bf16 bf16_t;
typedef __bf16 bf16x8 __attribute__((ext_vector_type(8)));
typedef __bf16 bf16x4 __attribute__((ext_vector_type(4)));
typedef short  s16x4  __attribute__((ext_vector_type(4)));
typedef float  f32x4  __attribute__((ext_vector_type(4)));

#define SEQ   2048
#define DM    1024
#define NH    16
#define DH    64
#define BATCH 2

__device__ __forceinline__ bf16x8 load8(const bf16_t* p) {
    return *reinterpret_cast<const bf16x8*>(p);
}
__device__ __forceinline__ f32x4 loadf4(const float* p) {
    return *reinterpret_cast<const f32x4*>(p);
}
// async global->LDS, 16B per lane. LDS dest = wave-uniform base + lane*16.
__device__ __forceinline__ void async16(const bf16_t* g, bf16_t* lds_base) {
    __builtin_amdgcn_global_load_lds(
        (const __attribute__((address_space(1))) void*)g,
        (__attribute__((address_space(3))) void*)lds_base, 16, 0, 0);
}
__device__ __forceinline__ float fast_exp2(float x) {
#if __has_builtin(__builtin_amdgcn_exp2f)
    return __builtin_amdgcn_exp2f(x);
#else
    return __expf(x * 0.69314718056f);
#endif
}
// swizzled 64-col bf16 LDS tile: logical (row, chunk8) at physical chunk8^(row&7)
__device__ __forceinline__ int swz(int row, int chunk) {
    return row * 64 + ((chunk ^ (row & 7)) * 8);
}

// ---------------------------------------------------------------------------
// tcvt helper (device): transpose+convert one 64x64 tile of w [1024][N] fp32
// into wT [N][1024] bf16.
// ---------------------------------------------------------------------------
__device__ __forceinline__ void tcvt_tile(
    const float* __restrict__ w, bf16_t* __restrict__ wT, int N,
    int n0, int k0, bf16_t (*tile)[65])
{
    const int tid = threadIdx.x;
#pragma unroll
    for (int i = 0; i < 4; ++i) {
        const int r = i * 16 + (tid >> 4);      // k-local
        const int c = (tid & 15) * 4;           // n-local
        f32x4 v = loadf4(w + (size_t)(k0 + r) * N + n0 + c);
#pragma unroll
        for (int j = 0; j < 4; ++j) tile[c + j][r] = (bf16_t)v[j];
    }
    __syncthreads();
#pragma unroll
    for (int i = 0; i < 4; ++i) {
        const int r = i * 16 + (tid >> 4);      // n-local
        const int c = (tid & 15) * 4;           // k-local
        ushort4 v;
        v.x = *(const uint16_t*)&tile[r][c];
        v.y = *(const uint16_t*)&tile[r][c + 1];
        v.z = *(const uint16_t*)&tile[r][c + 2];
        v.w = *(const uint16_t*)&tile[r][c + 3];
        *reinterpret_cast<ushort4*>(wT + (size_t)(n0 + r) * DM + k0 + c) = v;
    }
}

// ---------------------------------------------------------------------------
// pre: blocks [0,2048): x fp32 -> xb bf16 (8 elems/thread);
//      blocks [2048,2816): tcvt tiles of w_qkv (48 x 16 tiles).
// ---------------------------------------------------------------------------
__global__ __launch_bounds__(256) void pre_kernel(
    const float* __restrict__ x, bf16_t* __restrict__ xb,
    const float* __restrict__ w_qkv, bf16_t* __restrict__ wqkvT)
{
    __shared__ bf16_t tile[64][65];
    const int bid = blockIdx.x;
    if (bid < 2048) {
        const int i = (bid * 256 + threadIdx.x) * 8;
        f32x4 a = loadf4(x + i);
        f32x4 b = loadf4(x + i + 4);
        bf16x8 v;
#pragma unroll
        for (int j = 0; j < 4; ++j) { v[j] = (bf16_t)a[j]; v[4 + j] = (bf16_t)b[j]; }
        *reinterpret_cast<bf16x8*>(xb + i) = v;
    } else {
        const int t = bid - 2048;                // 0..767
        tcvt_tile(w_qkv, wqkvT, 3072, (t % 48) * 64, (t / 48) * 64, tile);
    }
}

// standalone tcvt (small-ws path)
__global__ __launch_bounds__(256) void tcvt_kernel(
    const float* __restrict__ w, bf16_t* __restrict__ wT, int N)
{
    __shared__ bf16_t tile[64][65];
    tcvt_tile(w, wT, N, blockIdx.x * 64, blockIdx.y * 64, tile);
}

// ---------------------------------------------------------------------------
// gemm8p: 256x256-tile bf16 GEMM for K1, K=1024, BK=64, 8 waves (2Mx4N).
// Ring of 4 half-tile slots (128 rows x 64 k) per tensor; slot(t,h)=(2t+h)&3.
// Per K-tile t, 4 phases q: q0 reads B-frags (8) + A-quad0 (4); q1-3 A-quads.
// Stages: A(t+1)h0 @q0, A(t+1)h1 + B(t+2)h0 @q1, B(t+2)h1 @q2 (all into
// slots freed by a previous phase's end barrier). vmcnt(4) @q3 (tail: 0).
// Outputs Q,K -> [B,H,T,64]; V -> VT [B,H,64,T] (same as old MODE 0).
// ---------------------------------------------------------------------------
__global__ __launch_bounds__(512) void gemm8p_kernel(
    const bf16_t* __restrict__ A, const bf16_t* __restrict__ BT,
    const float* __restrict__ bias,
    bf16_t* __restrict__ oq, bf16_t* __restrict__ ok, bf16_t* __restrict__ ov)
{
    __shared__ bf16_t sA[4 * 128 * 64];   // 64 KB ring
    __shared__ bf16_t sB[4 * 128 * 64];   // 64 KB ring

    const int tid  = threadIdx.x;
    const int lane = tid & 63;
    const int wv   = tid >> 6;            // 0..7
    const int wr   = wv >> 2;             // m half (0,1)
    const int wc   = wv & 3;              // n quarter (0..3)
    const int lq   = lane >> 4;
    const int lm   = lane & 15;

    // grid (12,16) = 192 blocks; class = flat&7 owns 2 m-tiles.
    const int flat = blockIdx.y * gridDim.x + blockIdx.x;
    const int cls  = flat & 7;
    const int q8   = flat >> 3;                    // 0..23
    const int mb   = (cls + 8 * (q8 & 1)) * 256;
    const int nb   = (q8 >> 1) * 256;

    const int scs  = ((lane & 7) ^ (lane >> 3)) * 8;   // swizzled source chunk

    // stage one half-tile (128x64) = 2 async16/thread; dest linear, src swz.
    auto stageA = [&](int tt, int h) {
        const int slot = (2 * tt + h) & 3;
        const int k0 = tt * 64;
#pragma unroll
        for (int j = 0; j < 2; ++j) {
            const int row = h * 128 + wv * 8 + (lane >> 3) + j * 64;
            async16(A + (size_t)(mb + row) * DM + k0 + scs,
                    &sA[slot * 8192 + (wv * 8 + j * 64) * 64]);
        }
    };
    auto stageB = [&](int tt, int h) {
        const int slot = (2 * tt + h) & 3;
        const int k0 = tt * 64;
#pragma unroll
        for (int j = 0; j < 2; ++j) {
            const int row = h * 128 + wv * 8 + (lane >> 3) + j * 64;
            async16(BT + (size_t)(nb + row) * DM + k0 + scs,
                    &sB[slot * 8192 + (wv * 8 + j * 64) * 64]);
        }
    };

    f32x4 acc[8][4];
#pragma unroll
    for (int f = 0; f < 8; ++f)
#pragma unroll
        for (int nf = 0; nf < 4; ++nf) acc[f][nf] = f32x4{0.f, 0.f, 0.f, 0.f};

    // prologue: B(0), A(0), B(1) staged; wait first 8 (B0+A0), leave B1 in flight
    stageB(0, 0); stageB(0, 1);
    stageA(0, 0); stageA(0, 1);
    stageB(1, 0); stageB(1, 1);
    asm volatile("s_waitcnt vmcnt(4)" ::: "memory");
    __builtin_amdgcn_sched_barrier(0);
    __builtin_amdgcn_s_barrier();

    for (int t = 0; t < 16; ++t) {
        const bf16_t* sAc = &sA[((2 * t + wr) & 3) * 8192];
        const bf16_t* sBc = &sB[((2 * t + (wc >> 1)) & 3) * 8192];
        bf16x8 bf[4][2];
#pragma unroll
        for (int q = 0; q < 4; ++q) {
            // stages into slots freed by an earlier phase's end barrier
            if (q == 0 && t + 1 < 16) stageA(t + 1, 0);
            if (q == 1 && t + 1 < 16) stageA(t + 1, 1);
            if (q == 1 && t + 2 < 16) stageB(t + 2, 0);
            if (q == 2 && t + 2 < 16) stageB(t + 2, 1);

            if (q == 0) {
#pragma unroll
                for (int nf = 0; nf < 4; ++nf)
#pragma unroll
                    for (int kh = 0; kh < 2; ++kh)
                        bf[nf][kh] = load8(
                            &sBc[swz((wc & 1) * 64 + nf * 16 + lm, kh * 4 + lq)]);
            }
            bf16x8 af[2][2];
#pragma unroll
            for (int j = 0; j < 2; ++j)
#pragma unroll
                for (int kh = 0; kh < 2; ++kh)
                    af[j][kh] = load8(
                        &sAc[swz((2 * q + j) * 16 + lm, kh * 4 + lq)]);

            if (q == 3) {
                // publish A(t+1) (and older B(t+1)) for next tile's readers
                if (t < 14) {
                    asm volatile("s_waitcnt vmcnt(4)" ::: "memory");
                } else if (t < 15) {
                    asm volatile("s_waitcnt vmcnt(0)" ::: "memory");
                }
                __builtin_amdgcn_sched_barrier(0);
            }
            __builtin_amdgcn_s_barrier();        // mid barrier

            __builtin_amdgcn_s_setprio(1);
#pragma unroll
            for (int kh = 0; kh < 2; ++kh)
#pragma unroll
                for (int j = 0; j < 2; ++j)
#pragma unroll
                    for (int nf = 0; nf < 4; ++nf)
                        acc[2 * q + j][nf] = __builtin_amdgcn_mfma_f32_16x16x32_bf16(
                            af[j][kh], bf[nf][kh], acc[2 * q + j][nf], 0, 0, 0);
            __builtin_amdgcn_s_setprio(0);
            __builtin_amdgcn_s_barrier();        // end barrier (frees slots)
        }
    }

    // epilogue: C/D layout col(n) = lm, row(m) = lq*4 + r
#pragma unroll
    for (int nf = 0; nf < 4; ++nf) {
        const int n = nb + wc * 64 + nf * 16 + lm;
        const float bv = bias[n];
        const int which = n >> 10;
        const int cc = n & 1023;
        const int h  = cc >> 6;
        const int d  = cc & 63;
        if (which == 2) {
#pragma unroll
            for (int f = 0; f < 8; ++f) {
                const int m0 = mb + wr * 128 + f * 16 + lq * 4;
                const int bb = m0 >> 11;
                const int t0 = m0 & 2047;
                bf16x4 w;
#pragma unroll
                for (int r = 0; r < 4; ++r) w[r] = (bf16_t)(acc[f][nf][r] + bv);
                *reinterpret_cast<bf16x4*>(
                    ov + ((size_t)(bb * NH + h) * DH + d) * SEQ + t0) = w;
            }
        } else {
            bf16_t* dst = (which == 0) ? oq : ok;
#pragma unroll
            for (int f = 0; f < 8; ++f)
#pragma unroll
                for (int r = 0; r < 4; ++r) {
                    const int m = mb + wr * 128 + f * 16 + lq * 4 + r;
                    const int bb = m >> 11;
                    const int t  = m & 2047;
                    dst[((size_t)(bb * NH + h) * SEQ + t) * DH + d] =
                        (bf16_t)(acc[f][nf][r] + bv);
                }
        }
    }
}

// ---------------------------------------------------------------------------
// 128xNT-tile bf16 GEMM (r15 form), K=1024, BK=64. Used for small-ws K1
// (fp32 A) and K3. gridDim.y MUST be 32.
// ---------------------------------------------------------------------------
template <typename TA, int MODE, int NT>
__global__ __launch_bounds__(256) void gemm_bt_kernel(
    const TA* __restrict__ A, const bf16_t* __restrict__ BT,
    const float* __restrict__ bias,
    float* __restrict__ outF,
    bf16_t* __restrict__ oq, bf16_t* __restrict__ ok, bf16_t* __restrict__ ov)
{
    constexpr int SAS = (sizeof(TA) == 4) ? 72 : 64;   // sA row stride (elems)
    constexpr int NB  = NT / 32;                       // b-subtiles per wave
    __shared__ bf16_t sA[128 * SAS];
    __shared__ bf16_t sB[NT * 64];

    const int tid  = threadIdx.x;
    const int lane = tid & 63;
    const int wv   = tid >> 6;
    const int lq   = lane >> 4;
    const int lm   = lane & 15;
    const int wm   = (wv >> 1) * 64;
    const int wn   = (wv & 1) * (NT / 2);

    const int flat = blockIdx.y * gridDim.x + blockIdx.x;
    const int cls  = flat & 7;
    const int q8   = flat >> 3;
    const int mb   = (cls + 8 * (q8 & 3)) * 128;
    const int nb   = (q8 >> 2) * NT;

    const int srow = lane >> 3;                    // 0..7
    const int scs  = ((lane & 7) ^ srow) * 8;      // swizzled source chunk

    f32x4 acc[4][NB];
#pragma unroll
    for (int a = 0; a < 4; ++a)
#pragma unroll
        for (int b = 0; b < NB; ++b) acc[a][b] = f32x4{0.f, 0.f, 0.f, 0.f};

    for (int it = 0; it < 16; ++it) {
        const int k0 = it * 64;
        if constexpr (sizeof(TA) == 4) {
            const int arow = tid >> 1;
            const int akc  = (tid & 1) * 32;
            const float* g = (const float*)A + (size_t)(mb + arow) * DM + k0 + akc;
            bf16_t* dst = &sA[arow * SAS + akc];
#pragma unroll
            for (int j = 0; j < 4; ++j) {
                f32x4 u0 = loadf4(g + j * 8);
                f32x4 u1 = loadf4(g + j * 8 + 4);
                bf16x8 w;
#pragma unroll
                for (int e = 0; e < 4; ++e) { w[e] = (bf16_t)u0[e]; w[4 + e] = (bf16_t)u1[e]; }
                *reinterpret_cast<bf16x8*>(dst + j * 8) = w;
            }
        } else {
#pragma unroll
            for (int r = 0; r < 4; ++r) {
                const int row = wv * 32 + r * 8 + srow;
                async16((const bf16_t*)A + (size_t)(mb + row) * DM + k0 + scs,
                        &sA[wv * 2048 + r * 512]);
            }
        }
#pragma unroll
        for (int r = 0; r < NT / 32; ++r) {
            const int row = wv * (NT / 4) + r * 8 + srow;
            async16(BT + (size_t)(nb + row) * DM + k0 + scs,
                    &sB[wv * (NT / 4) * 64 + r * 512]);
        }
        __syncthreads();
#pragma unroll
        for (int kh = 0; kh < 2; ++kh) {
            bf16x8 af[4], bfr[NB];
#pragma unroll
            for (int a = 0; a < 4; ++a) {
                if constexpr (sizeof(TA) == 4)
                    af[a] = load8(&sA[(wm + a * 16 + lm) * SAS + kh * 32 + lq * 8]);
                else
                    af[a] = load8(&sA[swz(wm + a * 16 + lm, kh * 4 + lq)]);
            }
#pragma unroll
            for (int b = 0; b < NB; ++b)
                bfr[b] = load8(&sB[swz(wn + b * 16 + lm, kh * 4 + lq)]);
#pragma unroll
            for (int a = 0; a < 4; ++a)
#pragma unroll
                for (int b = 0; b < NB; ++b)
                    acc[a][b] = __builtin_amdgcn_mfma_f32_16x16x32_bf16(
                        af[a], bfr[b], acc[a][b], 0, 0, 0);
        }
        __syncthreads();
    }

#pragma unroll
    for (int b = 0; b < NB; ++b) {
        const int n = nb + wn + b * 16 + lm;
        const float bv = bias[n];
        if (MODE == 0) {
            const int which = n >> 10;
            const int cc = n & 1023;
            const int h  = cc >> 6;
            const int d  = cc & 63;
            if (which == 2) {
#pragma unroll
                for (int a = 0; a < 4; ++a) {
                    const int m0 = mb + wm + a * 16 + lq * 4;
                    const int bb = m0 >> 11;
                    const int t0 = m0 & 2047;
                    bf16x4 w;
#pragma unroll
                    for (int r = 0; r < 4; ++r) w[r] = (bf16_t)(acc[a][b][r] + bv);
                    *reinterpret_cast<bf16x4*>(
                        ov + ((size_t)(bb * NH + h) * DH + d) * SEQ + t0) = w;
                }
            } else {
                bf16_t* dst = (which == 0) ? oq : ok;
#pragma unroll
                for (int a = 0; a < 4; ++a)
#pragma unroll
                    for (int r = 0; r < 4; ++r) {
                        const int m = mb + wm + a * 16 + lq * 4 + r;
                        const int bb = m >> 11;
                        const int t  = m & 2047;
                        dst[((size_t)(bb * NH + h) * SEQ + t) * DH + d] =
                            (bf16_t)(acc[a][b][r] + bv);
                    }
            }
        } else {
#pragma unroll
            for (int a = 0; a < 4; ++a)
#pragma unroll
                for (int r = 0; r < 4; ++r) {
                    const int m = mb + wm + a * 16 + lq * 4 + r;
                    outF[(size_t)m * DM + n] = acc[a][b][r] + bv;
                }
        }
    }
}

// ---------------------------------------------------------------------------
// Flash attention, S^T formulation, 128-row q-tiles, key-split, PAIRED
// staging, XCD-aware block swizzle (verified 43.3us r15 form, no setprio).
// ---------------------------------------------------------------------------
__global__ __launch_bounds__(256) void attn_kernel(
    const bf16_t* __restrict__ qbuf, const bf16_t* __restrict__ kbuf,
    const bf16_t* __restrict__ vtbuf, bf16_t* __restrict__ ybuf,
    bf16_t* __restrict__ p1, float* __restrict__ l0buf,
    float* __restrict__ l1buf, int split)
{
    __shared__ bf16_t sK[2][2 * 64 * 64];    // [buf][sub-tile][key][d], swizzled
    __shared__ bf16_t sVt[2][2 * 64 * 64];   // [buf][sub-tile][d][key], swizzled

    const int tid  = threadIdx.x;
    const int lane = tid & 63;
    const int wv   = tid >> 6;
    const int lq   = lane >> 4;
    const int lm   = lane & 15;

    const int p    = blockIdx.y * gridDim.x + blockIdx.x;
    const int slot = p >> 3;
    const int bh   = (p & 7) + ((slot & 3) << 3);
    const int uid  = slot >> 2;

    int qi, kt0, ktn, chunk1;
    if (!split)        { qi = 15 - uid;        kt0 = 0;  ktn = 2 * qi + 2;      chunk1 = 0; }
    else if (uid < 9)  { qi = 15 - uid;        kt0 = 0;  ktn = 16;              chunk1 = 0; }
    else if (uid < 17) { qi = 15 - (uid - 9);  kt0 = 16; ktn = 2 * qi + 2 - 16; chunk1 = 1; }
    else               { qi = 6 - (uid - 17);  kt0 = 0;  ktn = 2 * qi + 2;      chunk1 = 0; }
    const bool fin = !split || (!chunk1 && qi < 8);
    const int q_base = qi * 128;
    const int nps = ktn >> 1;                 // pairs (always integral)

    const size_t hb = (size_t)bh * SEQ * DH;
    const bf16_t* Q  = qbuf + hb;
    const bf16_t* K  = kbuf + hb;
    const bf16_t* VT = vtbuf + hb;            // [d][t] rows of length SEQ

    bf16x8 qf0[2], qf1[2];
#pragma unroll
    for (int ms = 0; ms < 2; ++ms) {
        const bf16_t* p_ = Q + (size_t)(q_base + wv * 32 + ms * 16 + lm) * DH + lq * 8;
        qf0[ms] = load8(p_);
        qf1[ms] = load8(p_ + 32);
    }

    f32x4 o[2][4];
    float ls[2];
#pragma unroll
    for (int ms = 0; ms < 2; ++ms) {
        ls[ms] = 0.f;
#pragma unroll
        for (int dc = 0; dc < 4; ++dc) o[ms][dc] = f32x4{0.f, 0.f, 0.f, 0.f};
    }

    const int srow = lane >> 3;
    const int scs  = ((lane & 7) ^ srow) * 8;

    {
        const int kb0 = kt0 * 64;
#pragma unroll
        for (int hf = 0; hf < 2; ++hf)
#pragma unroll
            for (int r = 0; r < 2; ++r) {
                async16(K + (size_t)(kb0 + hf * 64 + wv * 16 + r * 8 + srow) * DH + scs,
                        &sK[0][hf * 4096 + wv * 1024 + r * 512]);
                async16(VT + (size_t)(wv * 16 + r * 8 + srow) * SEQ + kb0 + hf * 64 + scs,
                        &sVt[0][hf * 4096 + wv * 1024 + r * 512]);
            }
    }
    __syncthreads();

    const float c1 = 0.125f * 1.44269504f;
    const float c2 = 10.0f  * 1.44269504f;

    for (int sp = 0; sp < nps; ++sp) {
        const int cb = sp & 1, nbuf = cb ^ 1;
        if (sp + 1 < nps) {
            const int kb2 = (kt0 + (sp + 1) * 2) * 64;
#pragma unroll
            for (int hf = 0; hf < 2; ++hf)
#pragma unroll
                for (int r = 0; r < 2; ++r) {
                    async16(K + (size_t)(kb2 + hf * 64 + wv * 16 + r * 8 + srow) * DH + scs,
                            &sK[nbuf][hf * 4096 + wv * 1024 + r * 512]);
                    async16(VT + (size_t)(wv * 16 + r * 8 + srow) * SEQ + kb2 + hf * 64 + scs,
                            &sVt[nbuf][hf * 4096 + wv * 1024 + r * 512]);
                }
        }

#pragma unroll
        for (int hf = 0; hf < 2; ++hf) {
            const int kb = (kt0 + sp * 2 + hf) * 64;
            const bf16_t* sKc = &sK[cb][hf * 4096];
            const bf16_t* sVc = &sVt[cb][hf * 4096];

            bf16x8 kf0[4], kf1[4];
#pragma unroll
            for (int c = 0; c < 4; ++c) {
                kf0[c] = load8(&sKc[swz(c * 16 + lm, lq)]);
                kf1[c] = load8(&sKc[swz(c * 16 + lm, lq + 4)]);
            }
            s16x4 vf[4][4];
#pragma unroll
            for (int dc = 0; dc < 4; ++dc)
#pragma unroll
                for (int c = 0; c < 4; ++c)
                    vf[dc][c] = *reinterpret_cast<const s16x4*>(
                        &sVc[swz(dc * 16 + lm, c * 2 + (lq >> 1)) + (lq & 1) * 4]);

#pragma unroll
            for (int ms = 0; ms < 2; ++ms) {
                const int rowlo = wv * 32 + ms * 16;
                if (q_base + rowlo + 15 < kb) continue;

                f32x4 s[4];
#pragma unroll
                for (int c = 0; c < 4; ++c) {
                    f32x4 z = f32x4{0.f, 0.f, 0.f, 0.f};
                    f32x4 t0 = __builtin_amdgcn_mfma_f32_16x16x32_bf16(kf0[c], qf0[ms], z, 0, 0, 0);
                    s[c] = __builtin_amdgcn_mfma_f32_16x16x32_bf16(kf1[c], qf1[ms], t0, 0, 0, 0);
                }

                const int q = q_base + rowlo + lm;
                float p4[4][4];
                if (kb + 63 > q_base + rowlo) {
#pragma unroll
                    for (int c = 0; c < 4; ++c)
#pragma unroll
                        for (int r = 0; r < 4; ++r) {
                            const int key = kb + c * 16 + lq * 4 + r;
                            float t = (key <= q) ? fmaf(s[c][r], c1, -c2) : -1e30f;
                            p4[c][r] = fast_exp2(t);
                        }
                } else {
#pragma unroll
                    for (int c = 0; c < 4; ++c)
#pragma unroll
                        for (int r = 0; r < 4; ++r)
                            p4[c][r] = fast_exp2(fmaf(s[c][r], c1, -c2));
                }
                float lsum = 0.f;
#pragma unroll
                for (int c = 0; c < 4; ++c)
                    lsum += (p4[c][0] + p4[c][1]) + (p4[c][2] + p4[c][3]);
                ls[ms] += lsum;

                s16x4 pf[4];
#pragma unroll
                for (int c = 0; c < 4; ++c) {
                    bf16x4 v;
#pragma unroll
                    for (int r = 0; r < 4; ++r) v[r] = (bf16_t)p4[c][r];
                    pf[c] = __builtin_bit_cast(s16x4, v);
                }

#pragma unroll
                for (int dc = 0; dc < 4; ++dc)
#pragma unroll
                    for (int c = 0; c < 4; ++c)
                        o[ms][dc] = __builtin_amdgcn_mfma_f32_16x16x16bf16_1k(
                            vf[dc][c], pf[c], o[ms][dc], 0, 0, 0);
            }
        }

        __syncthreads();
    }

    __syncthreads();
    bf16_t* sT = &sK[0][0];
    const int b = bh >> 4;
    const int h = bh & 15;
#pragma unroll
    for (int ms = 0; ms < 2; ++ms) {
        float l = ls[ms];
        l += __shfl_xor(l, 16);
        l += __shfl_xor(l, 32);
        const float inv = fin ? (1.0f / l) : 1.0f;
        if (!fin && lq == 0) {
            const int q = q_base + wv * 32 + ms * 16 + lm;
            float* lb = chunk1 ? l1buf : l0buf;
            lb[bh * 1024 + (q - 1024)] = l;
        }
#pragma unroll
        for (int dc = 0; dc < 4; ++dc)
#pragma unroll
            for (int r = 0; r < 4; ++r)
                sT[wv * 1152 + lm * 72 + dc * 16 + lq * 4 + r] =
                    (bf16_t)(o[ms][dc][r] * inv);
        const int t = q_base + wv * 32 + ms * 16 + (lane & 15);
        const bf16_t* src = &sT[wv * 1152 + (lane & 15) * 72 + (lane >> 4) * 16];
        bf16x8 y0 = load8(src);
        bf16x8 y1 = load8(src + 8);
        bf16_t* dst;
        if (chunk1)
            dst = p1 + ((size_t)(bh * 1024 + (t - 1024))) * 64 + (lane >> 4) * 16;
        else
            dst = ybuf + ((size_t)(b * SEQ + t)) * DM + h * DH + (lane >> 4) * 16;
        *reinterpret_cast<bf16x8*>(dst)     = y0;
        *reinterpret_cast<bf16x8*>(dst + 8) = y1;
    }
}

// ---------------------------------------------------------------------------
// post: blocks [0,1024): combine q>=1024 rows: y = (O0+O1)/(l0+l1);
//       blocks [1024,1280): tcvt tiles of w_out -> woutT (16 x 16 tiles).
// ---------------------------------------------------------------------------
__global__ __launch_bounds__(256) void post_kernel(
    bf16_t* __restrict__ yb, const bf16_t* __restrict__ p1,
    const float* __restrict__ l0, const float* __restrict__ l1,
    const float* __restrict__ w_out, bf16_t* __restrict__ woutT)
{
    __shared__ bf16_t tile[64][65];
    const int bid = blockIdx.x;
    if (bid < 1024) {
        const int idx = bid * 256 + threadIdx.x;
        const int d8  = (idx & 7) * 8;
        const int row = idx >> 3;
        const int ql  = row & 1023;
        const int bh  = row >> 10;
        const int q   = 1024 + ql;
        const int b   = bh >> 4, h = bh & 15;
        const float inv = 1.0f / (l0[row] + l1[row]);
        bf16_t* yp = yb + ((size_t)(b * SEQ + q)) * DM + h * DH + d8;
        const bf16_t* pp = p1 + (size_t)row * 64 + d8;
        bf16x8 a = load8(yp), c = load8(pp);
        bf16x8 oo;
#pragma unroll
        for (int j = 0; j < 8; ++j)
            oo[j] = (bf16_t)(((float)a[j] + (float)c[j]) * inv);
        *reinterpret_cast<bf16x8*>(yp) = oo;
    } else {
        const int t = bid - 1024;
        tcvt_tile(w_out, woutT, 1024, (t % 16) * 64, (t / 16) * 64, tile);
    }
}

// ---------------------------------------------------------------------------
extern "C" void kernel_launch(void* const* d_in, const int* in_sizes, int n_in,
                              void* d_out, int out_size, void* d_ws, size_t ws_size,
                              hipStream_t stream)
{
    const float* x     = (const float*)d_in[0];
    const float* w_qkv = (const float*)d_in[1];
    const float* b_qkv = (const float*)d_in[2];
    const float* w_out = (const float*)d_in[3];
    const float* b_out = (const float*)d_in[4];
    float* out = (float*)d_out;

    char* ws = (char*)d_ws;
    bf16_t* qb = (bf16_t*)(ws);                 // 0..8M
    bf16_t* kb = (bf16_t*)(ws + (8u << 20));    // 8..16M
    bf16_t* vb = (bf16_t*)(ws + (16u << 20));   // 16..24M  (VT [B,H,64,T])
    bf16_t* yb = (bf16_t*)(ws + (24u << 20));   // 24..32M
    bf16_t* woutT = qb;   // 2 MB; written after attention (qb dead by then)

    const bool bigws = (ws_size >= ((size_t)38 << 20));

    if (bigws) {
        bf16_t* xb    = yb;                                // dead before attn-Y
        bf16_t* wqkvT = (bf16_t*)(ws + (32u << 20));       // 32..38M (dead after K1)
        pre_kernel<<<dim3(2048 + 768), dim3(256), 0, stream>>>(x, xb, w_qkv, wqkvT);
        gemm8p_kernel<<<dim3(3072 / 256, 4096 / 256), dim3(512), 0, stream>>>(
            xb, wqkvT, b_qkv, qb, kb, vb);

        bf16_t* p1 = (bf16_t*)(ws + (32u << 20));              // 4 MB partials
        float*  l0 = (float*)(ws + (36u << 20));               // 128 KB
        float*  l1 = (float*)(ws + (36u << 20) + (128u << 10));// 128 KB
        attn_kernel<<<dim3(24, BATCH * NH), dim3(256), 0, stream>>>(
            qb, kb, vb, yb, p1, l0, l1, 1);
        post_kernel<<<dim3(1024 + 256), dim3(256), 0, stream>>>(
            yb, p1, l0, l1, w_out, woutT);
    } else {
        bf16_t* wqkvT = yb;
        tcvt_kernel<<<dim3(3072 / 64, 1024 / 64), dim3(256), 0, stream>>>(w_qkv, wqkvT, 3072);
        gemm_bt_kernel<float, 0, 128><<<dim3(3072 / 128, 4096 / 128), dim3(256), 0, stream>>>(
            x, wqkvT, b_qkv, nullptr, qb, kb, vb);
        attn_kernel<<<dim3(16, 32), dim3(256), 0, stream>>>(
            qb, kb, vb, yb, yb, nullptr, nullptr, 0);
        tcvt_kernel<<<dim3(1024 / 64, 1024 / 64), dim3(256), 0, stream>>>(w_out, woutT, 1024);
    }

    // K3: output projection, 128x64 tiles (512 blocks, 2/CU) -> d_out fp32
    gemm_bt_kernel<bf16_t, 1, 64><<<dim3(1024 / 64, 4096 / 128), dim3(256), 0, stream>>>(
        yb, woutT, b_out, out, nullptr, nullptr, nullptr);
}

// Round 17
// 183.394 us; speedup vs baseline: 1.0962x; 1.0962x over previous
//
#include <hip/hip_runtime.h>
#include <hip/hip_bf16.h>
#include <stdint.h>

// MHSA: B=2, T=2048, C=1024, H=16, d=64. fp32 in/out, bf16 MFMA, fp32 accum.
// FINAL (this session): the 185.3us-verified r15 source.
//   Session ledger (all harness-measured): r15=185.3 BEST; attn single-tile
//   dbuf 57.3 (worse); attn 8-wave 44.4 (worse); attn+setprio 43.5+ (null,
//   m190 confirmed); GEMM 4-param template K1 48.4 (rule-19 codegen);
//   GEMM dbuf K1 56.2 (m132 replay); GEMM 8-phase ring K1 53.4 @ 18% Mfma
//   (correct, 0 conflicts, but 1 blk/CU x 2 waves/SIMD lockstep can't hide
//   8 barriers/K-tile at K=1024/192 blocks - m201 regime doesn't transfer).
//   The r15 equilibrium (3 blk/CU, 2-barrier, cross-block overlap) beats
//   every expressible derivative at this problem scale.

typedef __bf16 bf16_t;
typedef __bf16 bf16x8 __attribute__((ext_vector_type(8)));
typedef __bf16 bf16x4 __attribute__((ext_vector_type(4)));
typedef short  s16x4  __attribute__((ext_vector_type(4)));
typedef float  f32x4  __attribute__((ext_vector_type(4)));

#define SEQ   2048
#define DM    1024
#define NH    16
#define DH    64
#define BATCH 2

__device__ __forceinline__ bf16x8 load8(const bf16_t* p) {
    return *reinterpret_cast<const bf16x8*>(p);
}
__device__ __forceinline__ f32x4 loadf4(const float* p) {
    return *reinterpret_cast<const f32x4*>(p);
}
// async global->LDS, 16B per lane. LDS dest = wave-uniform base + lane*16.
__device__ __forceinline__ void async16(const bf16_t* g, bf16_t* lds_base) {
    __builtin_amdgcn_global_load_lds(
        (const __attribute__((address_space(1))) void*)g,
        (__attribute__((address_space(3))) void*)lds_base, 16, 0, 0);
}
__device__ __forceinline__ float fast_exp2(float x) {
#if __has_builtin(__builtin_amdgcn_exp2f)
    return __builtin_amdgcn_exp2f(x);
#else
    return __expf(x * 0.69314718056f);
#endif
}
// swizzled 64x64 bf16 LDS tile: logical (row, chunk8) at physical chunk8^(row&7)
__device__ __forceinline__ int swz(int row, int chunk) {
    return row * 64 + ((chunk ^ (row & 7)) * 8);
}

// ---------------------------------------------------------------------------
// tcvt helper (device): transpose+convert one 64x64 tile of w [1024][N] fp32
// into wT [N][1024] bf16.
// ---------------------------------------------------------------------------
__device__ __forceinline__ void tcvt_tile(
    const float* __restrict__ w, bf16_t* __restrict__ wT, int N,
    int n0, int k0, bf16_t (*tile)[65])
{
    const int tid = threadIdx.x;
#pragma unroll
    for (int i = 0; i < 4; ++i) {
        const int r = i * 16 + (tid >> 4);      // k-local
        const int c = (tid & 15) * 4;           // n-local
        f32x4 v = loadf4(w + (size_t)(k0 + r) * N + n0 + c);
#pragma unroll
        for (int j = 0; j < 4; ++j) tile[c + j][r] = (bf16_t)v[j];
    }
    __syncthreads();
#pragma unroll
    for (int i = 0; i < 4; ++i) {
        const int r = i * 16 + (tid >> 4);      // n-local
        const int c = (tid & 15) * 4;           // k-local
        ushort4 v;
        v.x = *(const uint16_t*)&tile[r][c];
        v.y = *(const uint16_t*)&tile[r][c + 1];
        v.z = *(const uint16_t*)&tile[r][c + 2];
        v.w = *(const uint16_t*)&tile[r][c + 3];
        *reinterpret_cast<ushort4*>(wT + (size_t)(n0 + r) * DM + k0 + c) = v;
    }
}

// ---------------------------------------------------------------------------
// pre: blocks [0,2048): x fp32 -> xb bf16 (8 elems/thread);
//      blocks [2048,2816): tcvt tiles of w_qkv (48 x 16 tiles).
// ---------------------------------------------------------------------------
__global__ __launch_bounds__(256) void pre_kernel(
    const float* __restrict__ x, bf16_t* __restrict__ xb,
    const float* __restrict__ w_qkv, bf16_t* __restrict__ wqkvT)
{
    __shared__ bf16_t tile[64][65];
    const int bid = blockIdx.x;
    if (bid < 2048) {
        const int i = (bid * 256 + threadIdx.x) * 8;
        f32x4 a = loadf4(x + i);
        f32x4 b = loadf4(x + i + 4);
        bf16x8 v;
#pragma unroll
        for (int j = 0; j < 4; ++j) { v[j] = (bf16_t)a[j]; v[4 + j] = (bf16_t)b[j]; }
        *reinterpret_cast<bf16x8*>(xb + i) = v;
    } else {
        const int t = bid - 2048;                // 0..767
        tcvt_tile(w_qkv, wqkvT, 3072, (t % 48) * 64, (t / 48) * 64, tile);
    }
}

// standalone tcvt (small-ws path)
__global__ __launch_bounds__(256) void tcvt_kernel(
    const float* __restrict__ w, bf16_t* __restrict__ wT, int N)
{
    __shared__ bf16_t tile[64][65];
    tcvt_tile(w, wT, N, blockIdx.x * 64, blockIdx.y * 64, tile);
}

// ---------------------------------------------------------------------------
// 128xNT-tile bf16 GEMM, K=1024, BK=64. A [M,1024] row-major (TA = float:
// convert-in-staging, padded linear; TA = bf16: async16 + XOR swizzle).
// BT [N,1024] bf16 (async16 + XOR swizzle). gridDim.y MUST be 32.
// XCD decode: class=flat&7 -> m-rows {class, class+8, class+16, class+24};
// in-class consecutive blocks share a B-tile. Block 256 = 4 waves (2x2).
// MODE 0: Q,K -> [B,H,T,64]; V -> TRANSPOSED [B,H,64,T]. MODE 1: fp32 out.
// ---------------------------------------------------------------------------
template <typename TA, int MODE, int NT>
__global__ __launch_bounds__(256) void gemm_bt_kernel(
    const TA* __restrict__ A, const bf16_t* __restrict__ BT,
    const float* __restrict__ bias,
    float* __restrict__ outF,
    bf16_t* __restrict__ oq, bf16_t* __restrict__ ok, bf16_t* __restrict__ ov)
{
    constexpr int SAS = (sizeof(TA) == 4) ? 72 : 64;   // sA row stride (elems)
    constexpr int NB  = NT / 32;                       // b-subtiles per wave
    __shared__ bf16_t sA[128 * SAS];
    __shared__ bf16_t sB[NT * 64];

    const int tid  = threadIdx.x;
    const int lane = tid & 63;
    const int wv   = tid >> 6;
    const int lq   = lane >> 4;
    const int lm   = lane & 15;
    const int wm   = (wv >> 1) * 64;
    const int wn   = (wv & 1) * (NT / 2);

    // XCD-grouped decode (gridDim.y == 32): class = flat&7 owns 4 m-rows.
    const int flat = blockIdx.y * gridDim.x + blockIdx.x;
    const int cls  = flat & 7;
    const int q8   = flat >> 3;
    const int mb   = (cls + 8 * (q8 & 3)) * 128;
    const int nb   = (q8 >> 2) * NT;

    const int srow = lane >> 3;                    // 0..7
    const int scol = (lane & 7) * 8;               // linear chunk (fp32 path)
    const int scs  = ((lane & 7) ^ srow) * 8;      // swizzled source chunk

    f32x4 acc[4][NB];
#pragma unroll
    for (int a = 0; a < 4; ++a)
#pragma unroll
        for (int b = 0; b < NB; ++b) acc[a][b] = f32x4{0.f, 0.f, 0.f, 0.f};

    for (int it = 0; it < 16; ++it) {
        const int k0 = it * 64;
        if constexpr (sizeof(TA) == 4) {
            // fp32 A: padded linear layout (SAS=72 handles banks)
            const int arow = tid >> 1;
            const int akc  = (tid & 1) * 32;
            const float* g = (const float*)A + (size_t)(mb + arow) * DM + k0 + akc;
            bf16_t* dst = &sA[arow * SAS + akc];
#pragma unroll
            for (int j = 0; j < 4; ++j) {
                f32x4 u0 = loadf4(g + j * 8);
                f32x4 u1 = loadf4(g + j * 8 + 4);
                bf16x8 w;
#pragma unroll
                for (int e = 0; e < 4; ++e) { w[e] = (bf16_t)u0[e]; w[4 + e] = (bf16_t)u1[e]; }
                *reinterpret_cast<bf16x8*>(dst + j * 8) = w;
            }
        } else {
#pragma unroll
            for (int r = 0; r < 4; ++r) {
                const int row = wv * 32 + r * 8 + srow;
                async16((const bf16_t*)A + (size_t)(mb + row) * DM + k0 + scs,
                        &sA[wv * 2048 + r * 512]);
            }
        }
#pragma unroll
        for (int r = 0; r < NT / 32; ++r) {
            const int row = wv * (NT / 4) + r * 8 + srow;
            async16(BT + (size_t)(nb + row) * DM + k0 + scs,
                    &sB[wv * (NT / 4) * 64 + r * 512]);
        }
        __syncthreads();
#pragma unroll
        for (int kh = 0; kh < 2; ++kh) {
            bf16x8 af[4], bfr[NB];
#pragma unroll
            for (int a = 0; a < 4; ++a) {
                if constexpr (sizeof(TA) == 4)
                    af[a] = load8(&sA[(wm + a * 16 + lm) * SAS + kh * 32 + lq * 8]);
                else
                    af[a] = load8(&sA[swz(wm + a * 16 + lm, kh * 4 + lq)]);
            }
#pragma unroll
            for (int b = 0; b < NB; ++b)
                bfr[b] = load8(&sB[swz(wn + b * 16 + lm, kh * 4 + lq)]);
#pragma unroll
            for (int a = 0; a < 4; ++a)
#pragma unroll
                for (int b = 0; b < NB; ++b)
                    acc[a][b] = __builtin_amdgcn_mfma_f32_16x16x32_bf16(
                        af[a], bfr[b], acc[a][b], 0, 0, 0);
        }
        __syncthreads();
    }

    // epilogue: C/D layout col = lane&15, row = (lane>>4)*4 + r
#pragma unroll
    for (int b = 0; b < NB; ++b) {
        const int n = nb + wn + b * 16 + lm;
        const float bv = bias[n];
        if (MODE == 0) {
            const int which = n >> 10;
            const int cc = n & 1023;
            const int h  = cc >> 6;
            const int d  = cc & 63;
            if (which == 2) {
                // V -> VT[b,h,d,t]: 4 consecutive t per acc column, 8B store
#pragma unroll
                for (int a = 0; a < 4; ++a) {
                    const int m0 = mb + wm + a * 16 + lq * 4;
                    const int bb = m0 >> 11;
                    const int t0 = m0 & 2047;
                    bf16x4 w;
#pragma unroll
                    for (int r = 0; r < 4; ++r) w[r] = (bf16_t)(acc[a][b][r] + bv);
                    *reinterpret_cast<bf16x4*>(
                        ov + ((size_t)(bb * NH + h) * DH + d) * SEQ + t0) = w;
                }
            } else {
                bf16_t* dst = (which == 0) ? oq : ok;
#pragma unroll
                for (int a = 0; a < 4; ++a)
#pragma unroll
                    for (int r = 0; r < 4; ++r) {
                        const int m = mb + wm + a * 16 + lq * 4 + r;
                        const int bb = m >> 11;
                        const int t  = m & 2047;
                        dst[((size_t)(bb * NH + h) * SEQ + t) * DH + d] =
                            (bf16_t)(acc[a][b][r] + bv);
                    }
            }
        } else {
#pragma unroll
            for (int a = 0; a < 4; ++a)
#pragma unroll
                for (int r = 0; r < 4; ++r) {
                    const int m = mb + wm + a * 16 + lq * 4 + r;
                    outF[(size_t)m * DM + n] = acc[a][b][r] + bv;
                }
        }
    }
}

// ---------------------------------------------------------------------------
// Flash attention, S^T formulation, 128-row q-tiles, r9 key-split, PAIRED
// staging (r13), XCD-aware block swizzle (r14): flat block id p decodes to
// (bh, uid) with bh == p%8 class so every unit of a bh lands on one XCD;
// per-XCD L2 pins 4 bh x 512 KB of K/VT. Big units dispatch first per class.
// ---------------------------------------------------------------------------
__global__ __launch_bounds__(256) void attn_kernel(
    const bf16_t* __restrict__ qbuf, const bf16_t* __restrict__ kbuf,
    const bf16_t* __restrict__ vtbuf, bf16_t* __restrict__ ybuf,
    bf16_t* __restrict__ p1, float* __restrict__ l0buf,
    float* __restrict__ l1buf, int split)
{
    __shared__ bf16_t sK[2][2 * 64 * 64];    // [buf][sub-tile][key][d], swizzled
    __shared__ bf16_t sVt[2][2 * 64 * 64];   // [buf][sub-tile][d][key], swizzled

    const int tid  = threadIdx.x;
    const int lane = tid & 63;
    const int wv   = tid >> 6;
    const int lq   = lane >> 4;
    const int lm   = lane & 15;

    // XCD-aware decode: p%8 = XCD class; 4 bh per class; uid slow.
    const int p    = blockIdx.y * gridDim.x + blockIdx.x;
    const int slot = p >> 3;
    const int bh   = (p & 7) + ((slot & 3) << 3);
    const int uid  = slot >> 2;

    int qi, kt0, ktn, chunk1;
    if (!split)        { qi = 15 - uid;        kt0 = 0;  ktn = 2 * qi + 2;      chunk1 = 0; }
    else if (uid < 9)  { qi = 15 - uid;        kt0 = 0;  ktn = 16;              chunk1 = 0; }
    else if (uid < 17) { qi = 15 - (uid - 9);  kt0 = 16; ktn = 2 * qi + 2 - 16; chunk1 = 1; }
    else               { qi = 6 - (uid - 17);  kt0 = 0;  ktn = 2 * qi + 2;      chunk1 = 0; }
    const bool fin = !split || (!chunk1 && qi < 8);
    const int q_base = qi * 128;
    const int nps = ktn >> 1;                 // pairs (always integral)

    const size_t hb = (size_t)bh * SEQ * DH;
    const bf16_t* Q  = qbuf + hb;
    const bf16_t* K  = kbuf + hb;
    const bf16_t* VT = vtbuf + hb;            // [d][t] rows of length SEQ

    // Q fragments (B-operand of K.Q^T): lane lm = query, k = lq*8+j over d
    bf16x8 qf0[2], qf1[2];
#pragma unroll
    for (int ms = 0; ms < 2; ++ms) {
        const bf16_t* p_ = Q + (size_t)(q_base + wv * 32 + ms * 16 + lm) * DH + lq * 8;
        qf0[ms] = load8(p_);
        qf1[ms] = load8(p_ + 32);
    }

    f32x4 o[2][4];                     // O^T: [ms][d-subtile], d=lq*4+r, q=lm
    float ls[2];                       // lane-local row-sum (query = lm)
#pragma unroll
    for (int ms = 0; ms < 2; ++ms) {
        ls[ms] = 0.f;
#pragma unroll
        for (int dc = 0; dc < 4; ++dc) o[ms][dc] = f32x4{0.f, 0.f, 0.f, 0.f};
    }

    const int srow = lane >> 3;                    // staging row sub 0..7
    const int scs  = ((lane & 7) ^ srow) * 8;      // swizzled source chunk

    // prologue: stage pair 0 (keys [kt0*64, kt0*64+128))
    {
        const int kb0 = kt0 * 64;
#pragma unroll
        for (int hf = 0; hf < 2; ++hf)
#pragma unroll
            for (int r = 0; r < 2; ++r) {
                async16(K + (size_t)(kb0 + hf * 64 + wv * 16 + r * 8 + srow) * DH + scs,
                        &sK[0][hf * 4096 + wv * 1024 + r * 512]);
                async16(VT + (size_t)(wv * 16 + r * 8 + srow) * SEQ + kb0 + hf * 64 + scs,
                        &sVt[0][hf * 4096 + wv * 1024 + r * 512]);
            }
    }
    __syncthreads();

    const float c1 = 0.125f * 1.44269504f;   // scale * log2(e)
    const float c2 = 10.0f  * 1.44269504f;   // fixed shift * log2(e)

    for (int sp = 0; sp < nps; ++sp) {
        const int cb = sp & 1, nbuf = cb ^ 1;
        if (sp + 1 < nps) {
            const int kb2 = (kt0 + (sp + 1) * 2) * 64;
#pragma unroll
            for (int hf = 0; hf < 2; ++hf)
#pragma unroll
                for (int r = 0; r < 2; ++r) {
                    async16(K + (size_t)(kb2 + hf * 64 + wv * 16 + r * 8 + srow) * DH + scs,
                            &sK[nbuf][hf * 4096 + wv * 1024 + r * 512]);
                    async16(VT + (size_t)(wv * 16 + r * 8 + srow) * SEQ + kb2 + hf * 64 + scs,
                            &sVt[nbuf][hf * 4096 + wv * 1024 + r * 512]);
                }
        }

#pragma unroll
        for (int hf = 0; hf < 2; ++hf) {
            const int kb = (kt0 + sp * 2 + hf) * 64;
            const bf16_t* sKc = &sK[cb][hf * 4096];
            const bf16_t* sVc = &sVt[cb][hf * 4096];

            // K fragments (A-operand): lane lm = key, k over d; swizzled
            bf16x8 kf0[4], kf1[4];
#pragma unroll
            for (int c = 0; c < 4; ++c) {
                kf0[c] = load8(&sKc[swz(c * 16 + lm, lq)]);
                kf1[c] = load8(&sKc[swz(c * 16 + lm, lq + 4)]);
            }
            // V A-frags: A[m=d: dc*16+lm][k=key: c*16+lq*4+j] (b64, swizzled)
            s16x4 vf[4][4];
#pragma unroll
            for (int dc = 0; dc < 4; ++dc)
#pragma unroll
                for (int c = 0; c < 4; ++c)
                    vf[dc][c] = *reinterpret_cast<const s16x4*>(
                        &sVc[swz(dc * 16 + lm, c * 2 + (lq >> 1)) + (lq & 1) * 4]);

#pragma unroll
            for (int ms = 0; ms < 2; ++ms) {
                const int rowlo = wv * 32 + ms * 16;          // block-relative
                if (q_base + rowlo + 15 < kb) continue;       // fully masked

                // S^T: C[m=key: lq*4+r][n=query: lm]
                f32x4 s[4];
#pragma unroll
                for (int c = 0; c < 4; ++c) {
                    f32x4 z = f32x4{0.f, 0.f, 0.f, 0.f};
                    f32x4 t0 = __builtin_amdgcn_mfma_f32_16x16x32_bf16(kf0[c], qf0[ms], z, 0, 0, 0);
                    s[c] = __builtin_amdgcn_mfma_f32_16x16x32_bf16(kf1[c], qf1[ms], t0, 0, 0, 0);
                }

                const int q = q_base + rowlo + lm;    // this lane's query
                float p4[4][4];
                if (kb + 63 > q_base + rowlo) {       // diagonal region
#pragma unroll
                    for (int c = 0; c < 4; ++c)
#pragma unroll
                        for (int r = 0; r < 4; ++r) {
                            const int key = kb + c * 16 + lq * 4 + r;
                            float t = (key <= q) ? fmaf(s[c][r], c1, -c2) : -1e30f;
                            p4[c][r] = fast_exp2(t);
                        }
                } else {
#pragma unroll
                    for (int c = 0; c < 4; ++c)
#pragma unroll
                        for (int r = 0; r < 4; ++r)
                            p4[c][r] = fast_exp2(fmaf(s[c][r], c1, -c2));
                }
                float lsum = 0.f;
#pragma unroll
                for (int c = 0; c < 4; ++c)
                    lsum += (p4[c][0] + p4[c][1]) + (p4[c][2] + p4[c][3]);
                ls[ms] += lsum;

                // P -> bf16 B-frags (already in B-operand layout for K16 MFMA)
                s16x4 pf[4];
#pragma unroll
                for (int c = 0; c < 4; ++c) {
                    bf16x4 v;
#pragma unroll
                    for (int r = 0; r < 4; ++r) v[r] = (bf16_t)p4[c][r];
                    pf[c] = __builtin_bit_cast(s16x4, v);
                }

                // O^T += V^T . P   (16x16x16, K=16 per key-chunk c)
#pragma unroll
                for (int dc = 0; dc < 4; ++dc)
#pragma unroll
                    for (int c = 0; c < 4; ++c)
                        o[ms][dc] = __builtin_amdgcn_mfma_f32_16x16x16bf16_1k(
                            vf[dc][c], pf[c], o[ms][dc], 0, 0, 0);
            }
        }

        __syncthreads();
    }

    // epilogue: reduce row-sum over lq groups, normalize if finalizing,
    // transpose O^T -> row-major via LDS scratch (reuse sK), coalesced stores.
    __syncthreads();                       // all waves done with sK/sVt reads
    bf16_t* sT = &sK[0][0];                // [wave][16 q][72] scratch
    const int b = bh >> 4;
    const int h = bh & 15;
#pragma unroll
    for (int ms = 0; ms < 2; ++ms) {
        float l = ls[ms];
        l += __shfl_xor(l, 16);
        l += __shfl_xor(l, 32);
        const float inv = fin ? (1.0f / l) : 1.0f;
        if (!fin && lq == 0) {             // lanes 0..15 write this ms's l
            const int q = q_base + wv * 32 + ms * 16 + lm;
            float* lb = chunk1 ? l1buf : l0buf;
            lb[bh * 1024 + (q - 1024)] = l;
        }
#pragma unroll
        for (int dc = 0; dc < 4; ++dc)
#pragma unroll
            for (int r = 0; r < 4; ++r)
                sT[wv * 1152 + lm * 72 + dc * 16 + lq * 4 + r] =
                    (bf16_t)(o[ms][dc][r] * inv);
        // within-wave transpose readback: lane -> (q = lane&15, d-half = lane>>4)
        const int t = q_base + wv * 32 + ms * 16 + (lane & 15);
        const bf16_t* src = &sT[wv * 1152 + (lane & 15) * 72 + (lane >> 4) * 16];
        bf16x8 y0 = load8(src);
        bf16x8 y1 = load8(src + 8);
        bf16_t* dst;
        if (chunk1)
            dst = p1 + ((size_t)(bh * 1024 + (t - 1024))) * 64 + (lane >> 4) * 16;
        else
            dst = ybuf + ((size_t)(b * SEQ + t)) * DM + h * DH + (lane >> 4) * 16;
        *reinterpret_cast<bf16x8*>(dst)     = y0;
        *reinterpret_cast<bf16x8*>(dst + 8) = y1;
    }
}

// ---------------------------------------------------------------------------
// post: blocks [0,1024): combine q>=1024 rows: y = (O0+O1)/(l0+l1);
//       blocks [1024,1280): tcvt tiles of w_out -> woutT (16 x 16 tiles).
// ---------------------------------------------------------------------------
__global__ __launch_bounds__(256) void post_kernel(
    bf16_t* __restrict__ yb, const bf16_t* __restrict__ p1,
    const float* __restrict__ l0, const float* __restrict__ l1,
    const float* __restrict__ w_out, bf16_t* __restrict__ woutT)
{
    __shared__ bf16_t tile[64][65];
    const int bid = blockIdx.x;
    if (bid < 1024) {
        const int idx = bid * 256 + threadIdx.x;
        const int d8  = (idx & 7) * 8;
        const int row = idx >> 3;              // bh*1024 + (q-1024)
        const int ql  = row & 1023;
        const int bh  = row >> 10;
        const int q   = 1024 + ql;
        const int b   = bh >> 4, h = bh & 15;
        const float inv = 1.0f / (l0[row] + l1[row]);
        bf16_t* yp = yb + ((size_t)(b * SEQ + q)) * DM + h * DH + d8;
        const bf16_t* pp = p1 + (size_t)row * 64 + d8;
        bf16x8 a = load8(yp), c = load8(pp);
        bf16x8 oo;
#pragma unroll
        for (int j = 0; j < 8; ++j)
            oo[j] = (bf16_t)(((float)a[j] + (float)c[j]) * inv);
        *reinterpret_cast<bf16x8*>(yp) = oo;
    } else {
        const int t = bid - 1024;              // 0..255
        tcvt_tile(w_out, woutT, 1024, (t % 16) * 64, (t / 16) * 64, tile);
    }
}

// ---------------------------------------------------------------------------
extern "C" void kernel_launch(void* const* d_in, const int* in_sizes, int n_in,
                              void* d_out, int out_size, void* d_ws, size_t ws_size,
                              hipStream_t stream)
{
    const float* x     = (const float*)d_in[0];
    const float* w_qkv = (const float*)d_in[1];
    const float* b_qkv = (const float*)d_in[2];
    const float* w_out = (const float*)d_in[3];
    const float* b_out = (const float*)d_in[4];
    float* out = (float*)d_out;

    char* ws = (char*)d_ws;
    bf16_t* qb = (bf16_t*)(ws);                 // 0..8M
    bf16_t* kb = (bf16_t*)(ws + (8u << 20));    // 8..16M
    bf16_t* vb = (bf16_t*)(ws + (16u << 20));   // 16..24M  (VT [B,H,64,T])
    bf16_t* yb = (bf16_t*)(ws + (24u << 20));   // 24..32M
    bf16_t* woutT = qb;   // 2 MB; written after attention (qb dead by then)

    const bool bigws = (ws_size >= ((size_t)38 << 20));

    if (bigws) {
        bf16_t* xb    = yb;                                // dead before attn-Y
        bf16_t* wqkvT = (bf16_t*)(ws + (32u << 20));       // 32..38M (dead after K1)
        pre_kernel<<<dim3(2048 + 768), dim3(256), 0, stream>>>(x, xb, w_qkv, wqkvT);
        gemm_bt_kernel<bf16_t, 0, 128><<<dim3(3072 / 128, 4096 / 128), dim3(256), 0, stream>>>(
            xb, wqkvT, b_qkv, nullptr, qb, kb, vb);

        bf16_t* p1 = (bf16_t*)(ws + (32u << 20));              // 4 MB partials
        float*  l0 = (float*)(ws + (36u << 20));               // 128 KB
        float*  l1 = (float*)(ws + (36u << 20) + (128u << 10));// 128 KB
        attn_kernel<<<dim3(24, BATCH * NH), dim3(256), 0, stream>>>(
            qb, kb, vb, yb, p1, l0, l1, 1);
        post_kernel<<<dim3(1024 + 256), dim3(256), 0, stream>>>(
            yb, p1, l0, l1, w_out, woutT);
    } else {
        bf16_t* wqkvT = yb;
        tcvt_kernel<<<dim3(3072 / 64, 1024 / 64), dim3(256), 0, stream>>>(w_qkv, wqkvT, 3072);
        gemm_bt_kernel<float, 0, 128><<<dim3(3072 / 128, 4096 / 128), dim3(256), 0, stream>>>(
            x, wqkvT, b_qkv, nullptr, qb, kb, vb);
        attn_kernel<<<dim3(16, 32), dim3(256), 0, stream>>>(
            qb, kb, vb, yb, yb, nullptr, nullptr, 0);
        tcvt_kernel<<<dim3(1024 / 64, 1024 / 64), dim3(256), 0, stream>>>(w_out, woutT, 1024);
    }

    // K3: output projection, 128x64 tiles (512 blocks, 2/CU) -> d_out fp32
    gemm_bt_kernel<bf16_t, 1, 64><<<dim3(1024 / 64, 4096 / 128), dim3(256), 0, stream>>>(
        yb, woutT, b_out, out, nullptr, nullptr, nullptr);
}

// Round 18
// 182.812 us; speedup vs baseline: 1.0997x; 1.0032x over previous
//
#include <hip/hip_runtime.h>
#include <hip/hip_bf16.h>
#include <stdint.h>

// MHSA: B=2, T=2048, C=1024, H=16, d=64. fp32 in/out, bf16 MFMA, fp32 accum.
// FINAL (this session): the r15 source, harness-verified at 185.3us (r2),
// 188.0us (r11), 183.4us (r17) — stable 183-189us band.
//   Session ledger (all harness-measured): attn single-tile dbuf 57.3/disp
//   (worse); attn 8-wave 44.4 (null-to-worse); attn+setprio (null, m190);
//   GEMM 4-param template K1 48.4 (rule-19 codegen); GEMM dbuf K1 56.2
//   (m132 replay); GEMM 8-phase ring K1 53.4 @ 18% Mfma (correct, 0
//   conflicts, but 1 blk/CU x 2 waves/SIMD lockstep can't hide 8
//   barriers/K-tile at K=1024/192 blocks — m201 regime doesn't transfer).
//   NOTE r17: per-dispatch attn time swings 43->54us across machines with
//   identical source while totals stay ~183-189 — per-dispatch deltas <20%
//   are NOT attributable without within-build A/B (rule 13).
//   The r15 equilibrium (3 blk/CU, 2-barrier, cross-block overlap) beats
//   every expressible derivative at this problem scale.

typedef __bf16 bf16_t;
typedef __bf16 bf16x8 __attribute__((ext_vector_type(8)));
typedef __bf16 bf16x4 __attribute__((ext_vector_type(4)));
typedef short  s16x4  __attribute__((ext_vector_type(4)));
typedef float  f32x4  __attribute__((ext_vector_type(4)));

#define SEQ   2048
#define DM    1024
#define NH    16
#define DH    64
#define BATCH 2

__device__ __forceinline__ bf16x8 load8(const bf16_t* p) {
    return *reinterpret_cast<const bf16x8*>(p);
}
__device__ __forceinline__ f32x4 loadf4(const float* p) {
    return *reinterpret_cast<const f32x4*>(p);
}
// async global->LDS, 16B per lane. LDS dest = wave-uniform base + lane*16.
__device__ __forceinline__ void async16(const bf16_t* g, bf16_t* lds_base) {
    __builtin_amdgcn_global_load_lds(
        (const __attribute__((address_space(1))) void*)g,
        (__attribute__((address_space(3))) void*)lds_base, 16, 0, 0);
}
__device__ __forceinline__ float fast_exp2(float x) {
#if __has_builtin(__builtin_amdgcn_exp2f)
    return __builtin_amdgcn_exp2f(x);
#else
    return __expf(x * 0.69314718056f);
#endif
}
// swizzled 64x64 bf16 LDS tile: logical (row, chunk8) at physical chunk8^(row&7)
__device__ __forceinline__ int swz(int row, int chunk) {
    return row * 64 + ((chunk ^ (row & 7)) * 8);
}

// ---------------------------------------------------------------------------
// tcvt helper (device): transpose+convert one 64x64 tile of w [1024][N] fp32
// into wT [N][1024] bf16.
// ---------------------------------------------------------------------------
__device__ __forceinline__ void tcvt_tile(
    const float* __restrict__ w, bf16_t* __restrict__ wT, int N,
    int n0, int k0, bf16_t (*tile)[65])
{
    const int tid = threadIdx.x;
#pragma unroll
    for (int i = 0; i < 4; ++i) {
        const int r = i * 16 + (tid >> 4);      // k-local
        const int c = (tid & 15) * 4;           // n-local
        f32x4 v = loadf4(w + (size_t)(k0 + r) * N + n0 + c);
#pragma unroll
        for (int j = 0; j < 4; ++j) tile[c + j][r] = (bf16_t)v[j];
    }
    __syncthreads();
#pragma unroll
    for (int i = 0; i < 4; ++i) {
        const int r = i * 16 + (tid >> 4);      // n-local
        const int c = (tid & 15) * 4;           // k-local
        ushort4 v;
        v.x = *(const uint16_t*)&tile[r][c];
        v.y = *(const uint16_t*)&tile[r][c + 1];
        v.z = *(const uint16_t*)&tile[r][c + 2];
        v.w = *(const uint16_t*)&tile[r][c + 3];
        *reinterpret_cast<ushort4*>(wT + (size_t)(n0 + r) * DM + k0 + c) = v;
    }
}

// ---------------------------------------------------------------------------
// pre: blocks [0,2048): x fp32 -> xb bf16 (8 elems/thread);
//      blocks [2048,2816): tcvt tiles of w_qkv (48 x 16 tiles).
// ---------------------------------------------------------------------------
__global__ __launch_bounds__(256) void pre_kernel(
    const float* __restrict__ x, bf16_t* __restrict__ xb,
    const float* __restrict__ w_qkv, bf16_t* __restrict__ wqkvT)
{
    __shared__ bf16_t tile[64][65];
    const int bid = blockIdx.x;
    if (bid < 2048) {
        const int i = (bid * 256 + threadIdx.x) * 8;
        f32x4 a = loadf4(x + i);
        f32x4 b = loadf4(x + i + 4);
        bf16x8 v;
#pragma unroll
        for (int j = 0; j < 4; ++j) { v[j] = (bf16_t)a[j]; v[4 + j] = (bf16_t)b[j]; }
        *reinterpret_cast<bf16x8*>(xb + i) = v;
    } else {
        const int t = bid - 2048;                // 0..767
        tcvt_tile(w_qkv, wqkvT, 3072, (t % 48) * 64, (t / 48) * 64, tile);
    }
}

// standalone tcvt (small-ws path)
__global__ __launch_bounds__(256) void tcvt_kernel(
    const float* __restrict__ w, bf16_t* __restrict__ wT, int N)
{
    __shared__ bf16_t tile[64][65];
    tcvt_tile(w, wT, N, blockIdx.x * 64, blockIdx.y * 64, tile);
}

// ---------------------------------------------------------------------------
// 128xNT-tile bf16 GEMM, K=1024, BK=64. A [M,1024] row-major (TA = float:
// convert-in-staging, padded linear; TA = bf16: async16 + XOR swizzle).
// BT [N,1024] bf16 (async16 + XOR swizzle). gridDim.y MUST be 32.
// XCD decode: class=flat&7 -> m-rows {class, class+8, class+16, class+24};
// in-class consecutive blocks share a B-tile. Block 256 = 4 waves (2x2).
// MODE 0: Q,K -> [B,H,T,64]; V -> TRANSPOSED [B,H,64,T]. MODE 1: fp32 out.
// ---------------------------------------------------------------------------
template <typename TA, int MODE, int NT>
__global__ __launch_bounds__(256) void gemm_bt_kernel(
    const TA* __restrict__ A, const bf16_t* __restrict__ BT,
    const float* __restrict__ bias,
    float* __restrict__ outF,
    bf16_t* __restrict__ oq, bf16_t* __restrict__ ok, bf16_t* __restrict__ ov)
{
    constexpr int SAS = (sizeof(TA) == 4) ? 72 : 64;   // sA row stride (elems)
    constexpr int NB  = NT / 32;                       // b-subtiles per wave
    __shared__ bf16_t sA[128 * SAS];
    __shared__ bf16_t sB[NT * 64];

    const int tid  = threadIdx.x;
    const int lane = tid & 63;
    const int wv   = tid >> 6;
    const int lq   = lane >> 4;
    const int lm   = lane & 15;
    const int wm   = (wv >> 1) * 64;
    const int wn   = (wv & 1) * (NT / 2);

    // XCD-grouped decode (gridDim.y == 32): class = flat&7 owns 4 m-rows.
    const int flat = blockIdx.y * gridDim.x + blockIdx.x;
    const int cls  = flat & 7;
    const int q8   = flat >> 3;
    const int mb   = (cls + 8 * (q8 & 3)) * 128;
    const int nb   = (q8 >> 2) * NT;

    const int srow = lane >> 3;                    // 0..7
    const int scol = (lane & 7) * 8;               // linear chunk (fp32 path)
    const int scs  = ((lane & 7) ^ srow) * 8;      // swizzled source chunk

    f32x4 acc[4][NB];
#pragma unroll
    for (int a = 0; a < 4; ++a)
#pragma unroll
        for (int b = 0; b < NB; ++b) acc[a][b] = f32x4{0.f, 0.f, 0.f, 0.f};

    for (int it = 0; it < 16; ++it) {
        const int k0 = it * 64;
        if constexpr (sizeof(TA) == 4) {
            // fp32 A: padded linear layout (SAS=72 handles banks)
            const int arow = tid >> 1;
            const int akc  = (tid & 1) * 32;
            const float* g = (const float*)A + (size_t)(mb + arow) * DM + k0 + akc;
            bf16_t* dst = &sA[arow * SAS + akc];
#pragma unroll
            for (int j = 0; j < 4; ++j) {
                f32x4 u0 = loadf4(g + j * 8);
                f32x4 u1 = loadf4(g + j * 8 + 4);
                bf16x8 w;
#pragma unroll
                for (int e = 0; e < 4; ++e) { w[e] = (bf16_t)u0[e]; w[4 + e] = (bf16_t)u1[e]; }
                *reinterpret_cast<bf16x8*>(dst + j * 8) = w;
            }
        } else {
#pragma unroll
            for (int r = 0; r < 4; ++r) {
                const int row = wv * 32 + r * 8 + srow;
                async16((const bf16_t*)A + (size_t)(mb + row) * DM + k0 + scs,
                        &sA[wv * 2048 + r * 512]);
            }
        }
#pragma unroll
        for (int r = 0; r < NT / 32; ++r) {
            const int row = wv * (NT / 4) + r * 8 + srow;
            async16(BT + (size_t)(nb + row) * DM + k0 + scs,
                    &sB[wv * (NT / 4) * 64 + r * 512]);
        }
        __syncthreads();
#pragma unroll
        for (int kh = 0; kh < 2; ++kh) {
            bf16x8 af[4], bfr[NB];
#pragma unroll
            for (int a = 0; a < 4; ++a) {
                if constexpr (sizeof(TA) == 4)
                    af[a] = load8(&sA[(wm + a * 16 + lm) * SAS + kh * 32 + lq * 8]);
                else
                    af[a] = load8(&sA[swz(wm + a * 16 + lm, kh * 4 + lq)]);
            }
#pragma unroll
            for (int b = 0; b < NB; ++b)
                bfr[b] = load8(&sB[swz(wn + b * 16 + lm, kh * 4 + lq)]);
#pragma unroll
            for (int a = 0; a < 4; ++a)
#pragma unroll
                for (int b = 0; b < NB; ++b)
                    acc[a][b] = __builtin_amdgcn_mfma_f32_16x16x32_bf16(
                        af[a], bfr[b], acc[a][b], 0, 0, 0);
        }
        __syncthreads();
    }

    // epilogue: C/D layout col = lane&15, row = (lane>>4)*4 + r
#pragma unroll
    for (int b = 0; b < NB; ++b) {
        const int n = nb + wn + b * 16 + lm;
        const float bv = bias[n];
        if (MODE == 0) {
            const int which = n >> 10;
            const int cc = n & 1023;
            const int h  = cc >> 6;
            const int d  = cc & 63;
            if (which == 2) {
                // V -> VT[b,h,d,t]: 4 consecutive t per acc column, 8B store
#pragma unroll
                for (int a = 0; a < 4; ++a) {
                    const int m0 = mb + wm + a * 16 + lq * 4;
                    const int bb = m0 >> 11;
                    const int t0 = m0 & 2047;
                    bf16x4 w;
#pragma unroll
                    for (int r = 0; r < 4; ++r) w[r] = (bf16_t)(acc[a][b][r] + bv);
                    *reinterpret_cast<bf16x4*>(
                        ov + ((size_t)(bb * NH + h) * DH + d) * SEQ + t0) = w;
                }
            } else {
                bf16_t* dst = (which == 0) ? oq : ok;
#pragma unroll
                for (int a = 0; a < 4; ++a)
#pragma unroll
                    for (int r = 0; r < 4; ++r) {
                        const int m = mb + wm + a * 16 + lq * 4 + r;
                        const int bb = m >> 11;
                        const int t  = m & 2047;
                        dst[((size_t)(bb * NH + h) * SEQ + t) * DH + d] =
                            (bf16_t)(acc[a][b][r] + bv);
                    }
            }
        } else {
#pragma unroll
            for (int a = 0; a < 4; ++a)
#pragma unroll
                for (int r = 0; r < 4; ++r) {
                    const int m = mb + wm + a * 16 + lq * 4 + r;
                    outF[(size_t)m * DM + n] = acc[a][b][r] + bv;
                }
        }
    }
}

// ---------------------------------------------------------------------------
// Flash attention, S^T formulation, 128-row q-tiles, r9 key-split, PAIRED
// staging (r13), XCD-aware block swizzle (r14): flat block id p decodes to
// (bh, uid) with bh == p%8 class so every unit of a bh lands on one XCD;
// per-XCD L2 pins 4 bh x 512 KB of K/VT. Big units dispatch first per class.
// ---------------------------------------------------------------------------
__global__ __launch_bounds__(256) void attn_kernel(
    const bf16_t* __restrict__ qbuf, const bf16_t* __restrict__ kbuf,
    const bf16_t* __restrict__ vtbuf, bf16_t* __restrict__ ybuf,
    bf16_t* __restrict__ p1, float* __restrict__ l0buf,
    float* __restrict__ l1buf, int split)
{
    __shared__ bf16_t sK[2][2 * 64 * 64];    // [buf][sub-tile][key][d], swizzled
    __shared__ bf16_t sVt[2][2 * 64 * 64];   // [buf][sub-tile][d][key], swizzled

    const int tid  = threadIdx.x;
    const int lane = tid & 63;
    const int wv   = tid >> 6;
    const int lq   = lane >> 4;
    const int lm   = lane & 15;

    // XCD-aware decode: p%8 = XCD class; 4 bh per class; uid slow.
    const int p    = blockIdx.y * gridDim.x + blockIdx.x;
    const int slot = p >> 3;
    const int bh   = (p & 7) + ((slot & 3) << 3);
    const int uid  = slot >> 2;

    int qi, kt0, ktn, chunk1;
    if (!split)        { qi = 15 - uid;        kt0 = 0;  ktn = 2 * qi + 2;      chunk1 = 0; }
    else if (uid < 9)  { qi = 15 - uid;        kt0 = 0;  ktn = 16;              chunk1 = 0; }
    else if (uid < 17) { qi = 15 - (uid - 9);  kt0 = 16; ktn = 2 * qi + 2 - 16; chunk1 = 1; }
    else               { qi = 6 - (uid - 17);  kt0 = 0;  ktn = 2 * qi + 2;      chunk1 = 0; }
    const bool fin = !split || (!chunk1 && qi < 8);
    const int q_base = qi * 128;
    const int nps = ktn >> 1;                 // pairs (always integral)

    const size_t hb = (size_t)bh * SEQ * DH;
    const bf16_t* Q  = qbuf + hb;
    const bf16_t* K  = kbuf + hb;
    const bf16_t* VT = vtbuf + hb;            // [d][t] rows of length SEQ

    // Q fragments (B-operand of K.Q^T): lane lm = query, k = lq*8+j over d
    bf16x8 qf0[2], qf1[2];
#pragma unroll
    for (int ms = 0; ms < 2; ++ms) {
        const bf16_t* p_ = Q + (size_t)(q_base + wv * 32 + ms * 16 + lm) * DH + lq * 8;
        qf0[ms] = load8(p_);
        qf1[ms] = load8(p_ + 32);
    }

    f32x4 o[2][4];                     // O^T: [ms][d-subtile], d=lq*4+r, q=lm
    float ls[2];                       // lane-local row-sum (query = lm)
#pragma unroll
    for (int ms = 0; ms < 2; ++ms) {
        ls[ms] = 0.f;
#pragma unroll
        for (int dc = 0; dc < 4; ++dc) o[ms][dc] = f32x4{0.f, 0.f, 0.f, 0.f};
    }

    const int srow = lane >> 3;                    // staging row sub 0..7
    const int scs  = ((lane & 7) ^ srow) * 8;      // swizzled source chunk

    // prologue: stage pair 0 (keys [kt0*64, kt0*64+128))
    {
        const int kb0 = kt0 * 64;
#pragma unroll
        for (int hf = 0; hf < 2; ++hf)
#pragma unroll
            for (int r = 0; r < 2; ++r) {
                async16(K + (size_t)(kb0 + hf * 64 + wv * 16 + r * 8 + srow) * DH + scs,
                        &sK[0][hf * 4096 + wv * 1024 + r * 512]);
                async16(VT + (size_t)(wv * 16 + r * 8 + srow) * SEQ + kb0 + hf * 64 + scs,
                        &sVt[0][hf * 4096 + wv * 1024 + r * 512]);
            }
    }
    __syncthreads();

    const float c1 = 0.125f * 1.44269504f;   // scale * log2(e)
    const float c2 = 10.0f  * 1.44269504f;   // fixed shift * log2(e)

    for (int sp = 0; sp < nps; ++sp) {
        const int cb = sp & 1, nbuf = cb ^ 1;
        if (sp + 1 < nps) {
            const int kb2 = (kt0 + (sp + 1) * 2) * 64;
#pragma unroll
            for (int hf = 0; hf < 2; ++hf)
#pragma unroll
                for (int r = 0; r < 2; ++r) {
                    async16(K + (size_t)(kb2 + hf * 64 + wv * 16 + r * 8 + srow) * DH + scs,
                            &sK[nbuf][hf * 4096 + wv * 1024 + r * 512]);
                    async16(VT + (size_t)(wv * 16 + r * 8 + srow) * SEQ + kb2 + hf * 64 + scs,
                            &sVt[nbuf][hf * 4096 + wv * 1024 + r * 512]);
                }
        }

#pragma unroll
        for (int hf = 0; hf < 2; ++hf) {
            const int kb = (kt0 + sp * 2 + hf) * 64;
            const bf16_t* sKc = &sK[cb][hf * 4096];
            const bf16_t* sVc = &sVt[cb][hf * 4096];

            // K fragments (A-operand): lane lm = key, k over d; swizzled
            bf16x8 kf0[4], kf1[4];
#pragma unroll
            for (int c = 0; c < 4; ++c) {
                kf0[c] = load8(&sKc[swz(c * 16 + lm, lq)]);
                kf1[c] = load8(&sKc[swz(c * 16 + lm, lq + 4)]);
            }
            // V A-frags: A[m=d: dc*16+lm][k=key: c*16+lq*4+j] (b64, swizzled)
            s16x4 vf[4][4];
#pragma unroll
            for (int dc = 0; dc < 4; ++dc)
#pragma unroll
                for (int c = 0; c < 4; ++c)
                    vf[dc][c] = *reinterpret_cast<const s16x4*>(
                        &sVc[swz(dc * 16 + lm, c * 2 + (lq >> 1)) + (lq & 1) * 4]);

#pragma unroll
            for (int ms = 0; ms < 2; ++ms) {
                const int rowlo = wv * 32 + ms * 16;          // block-relative
                if (q_base + rowlo + 15 < kb) continue;       // fully masked

                // S^T: C[m=key: lq*4+r][n=query: lm]
                f32x4 s[4];
#pragma unroll
                for (int c = 0; c < 4; ++c) {
                    f32x4 z = f32x4{0.f, 0.f, 0.f, 0.f};
                    f32x4 t0 = __builtin_amdgcn_mfma_f32_16x16x32_bf16(kf0[c], qf0[ms], z, 0, 0, 0);
                    s[c] = __builtin_amdgcn_mfma_f32_16x16x32_bf16(kf1[c], qf1[ms], t0, 0, 0, 0);
                }

                const int q = q_base + rowlo + lm;    // this lane's query
                float p4[4][4];
                if (kb + 63 > q_base + rowlo) {       // diagonal region
#pragma unroll
                    for (int c = 0; c < 4; ++c)
#pragma unroll
                        for (int r = 0; r < 4; ++r) {
                            const int key = kb + c * 16 + lq * 4 + r;
                            float t = (key <= q) ? fmaf(s[c][r], c1, -c2) : -1e30f;
                            p4[c][r] = fast_exp2(t);
                        }
                } else {
#pragma unroll
                    for (int c = 0; c < 4; ++c)
#pragma unroll
                        for (int r = 0; r < 4; ++r)
                            p4[c][r] = fast_exp2(fmaf(s[c][r], c1, -c2));
                }
                float lsum = 0.f;
#pragma unroll
                for (int c = 0; c < 4; ++c)
                    lsum += (p4[c][0] + p4[c][1]) + (p4[c][2] + p4[c][3]);
                ls[ms] += lsum;

                // P -> bf16 B-frags (already in B-operand layout for K16 MFMA)
                s16x4 pf[4];
#pragma unroll
                for (int c = 0; c < 4; ++c) {
                    bf16x4 v;
#pragma unroll
                    for (int r = 0; r < 4; ++r) v[r] = (bf16_t)p4[c][r];
                    pf[c] = __builtin_bit_cast(s16x4, v);
                }

                // O^T += V^T . P   (16x16x16, K=16 per key-chunk c)
#pragma unroll
                for (int dc = 0; dc < 4; ++dc)
#pragma unroll
                    for (int c = 0; c < 4; ++c)
                        o[ms][dc] = __builtin_amdgcn_mfma_f32_16x16x16bf16_1k(
                            vf[dc][c], pf[c], o[ms][dc], 0, 0, 0);
            }
        }

        __syncthreads();
    }

    // epilogue: reduce row-sum over lq groups, normalize if finalizing,
    // transpose O^T -> row-major via LDS scratch (reuse sK), coalesced stores.
    __syncthreads();                       // all waves done with sK/sVt reads
    bf16_t* sT = &sK[0][0];                // [wave][16 q][72] scratch
    const int b = bh >> 4;
    const int h = bh & 15;
#pragma unroll
    for (int ms = 0; ms < 2; ++ms) {
        float l = ls[ms];
        l += __shfl_xor(l, 16);
        l += __shfl_xor(l, 32);
        const float inv = fin ? (1.0f / l) : 1.0f;
        if (!fin && lq == 0) {             // lanes 0..15 write this ms's l
            const int q = q_base + wv * 32 + ms * 16 + lm;
            float* lb = chunk1 ? l1buf : l0buf;
            lb[bh * 1024 + (q - 1024)] = l;
        }
#pragma unroll
        for (int dc = 0; dc < 4; ++dc)
#pragma unroll
            for (int r = 0; r < 4; ++r)
                sT[wv * 1152 + lm * 72 + dc * 16 + lq * 4 + r] =
                    (bf16_t)(o[ms][dc][r] * inv);
        // within-wave transpose readback: lane -> (q = lane&15, d-half = lane>>4)
        const int t = q_base + wv * 32 + ms * 16 + (lane & 15);
        const bf16_t* src = &sT[wv * 1152 + (lane & 15) * 72 + (lane >> 4) * 16];
        bf16x8 y0 = load8(src);
        bf16x8 y1 = load8(src + 8);
        bf16_t* dst;
        if (chunk1)
            dst = p1 + ((size_t)(bh * 1024 + (t - 1024))) * 64 + (lane >> 4) * 16;
        else
            dst = ybuf + ((size_t)(b * SEQ + t)) * DM + h * DH + (lane >> 4) * 16;
        *reinterpret_cast<bf16x8*>(dst)     = y0;
        *reinterpret_cast<bf16x8*>(dst + 8) = y1;
    }
}

// ---------------------------------------------------------------------------
// post: blocks [0,1024): combine q>=1024 rows: y = (O0+O1)/(l0+l1);
//       blocks [1024,1280): tcvt tiles of w_out -> woutT (16 x 16 tiles).
// ---------------------------------------------------------------------------
__global__ __launch_bounds__(256) void post_kernel(
    bf16_t* __restrict__ yb, const bf16_t* __restrict__ p1,
    const float* __restrict__ l0, const float* __restrict__ l1,
    const float* __restrict__ w_out, bf16_t* __restrict__ woutT)
{
    __shared__ bf16_t tile[64][65];
    const int bid = blockIdx.x;
    if (bid < 1024) {
        const int idx = bid * 256 + threadIdx.x;
        const int d8  = (idx & 7) * 8;
        const int row = idx >> 3;              // bh*1024 + (q-1024)
        const int ql  = row & 1023;
        const int bh  = row >> 10;
        const int q   = 1024 + ql;
        const int b   = bh >> 4, h = bh & 15;
        const float inv = 1.0f / (l0[row] + l1[row]);
        bf16_t* yp = yb + ((size_t)(b * SEQ + q)) * DM + h * DH + d8;
        const bf16_t* pp = p1 + (size_t)row * 64 + d8;
        bf16x8 a = load8(yp), c = load8(pp);
        bf16x8 oo;
#pragma unroll
        for (int j = 0; j < 8; ++j)
            oo[j] = (bf16_t)(((float)a[j] + (float)c[j]) * inv);
        *reinterpret_cast<bf16x8*>(yp) = oo;
    } else {
        const int t = bid - 1024;              // 0..255
        tcvt_tile(w_out, woutT, 1024, (t % 16) * 64, (t / 16) * 64, tile);
    }
}

// ---------------------------------------------------------------------------
extern "C" void kernel_launch(void* const* d_in, const int* in_sizes, int n_in,
                              void* d_out, int out_size, void* d_ws, size_t ws_size,
                              hipStream_t stream)
{
    const float* x     = (const float*)d_in[0];
    const float* w_qkv = (const float*)d_in[1];
    const float* b_qkv = (const float*)d_in[2];
    const float* w_out = (const float*)d_in[3];
    const float* b_out = (const float*)d_in[4];
    float* out = (float*)d_out;

    char* ws = (char*)d_ws;
    bf16_t* qb = (bf16_t*)(ws);                 // 0..8M
    bf16_t* kb = (bf16_t*)(ws + (8u << 20));    // 8..16M
    bf16_t* vb = (bf16_t*)(ws + (16u << 20));   // 16..24M  (VT [B,H,64,T])
    bf16_t* yb = (bf16_t*)(ws + (24u << 20));   // 24..32M
    bf16_t* woutT = qb;   // 2 MB; written after attention (qb dead by then)

    const bool bigws = (ws_size >= ((size_t)38 << 20));

    if (bigws) {
        bf16_t* xb    = yb;                                // dead before attn-Y
        bf16_t* wqkvT = (bf16_t*)(ws + (32u << 20));       // 32..38M (dead after K1)
        pre_kernel<<<dim3(2048 + 768), dim3(256), 0, stream>>>(x, xb, w_qkv, wqkvT);
        gemm_bt_kernel<bf16_t, 0, 128><<<dim3(3072 / 128, 4096 / 128), dim3(256), 0, stream>>>(
            xb, wqkvT, b_qkv, nullptr, qb, kb, vb);

        bf16_t* p1 = (bf16_t*)(ws + (32u << 20));              // 4 MB partials
        float*  l0 = (float*)(ws + (36u << 20));               // 128 KB
        float*  l1 = (float*)(ws + (36u << 20) + (128u << 10));// 128 KB
        attn_kernel<<<dim3(24, BATCH * NH), dim3(256), 0, stream>>>(
            qb, kb, vb, yb, p1, l0, l1, 1);
        post_kernel<<<dim3(1024 + 256), dim3(256), 0, stream>>>(
            yb, p1, l0, l1, w_out, woutT);
    } else {
        bf16_t* wqkvT = yb;
        tcvt_kernel<<<dim3(3072 / 64, 1024 / 64), dim3(256), 0, stream>>>(w_qkv, wqkvT, 3072);
        gemm_bt_kernel<float, 0, 128><<<dim3(3072 / 128, 4096 / 128), dim3(256), 0, stream>>>(
            x, wqkvT, b_qkv, nullptr, qb, kb, vb);
        attn_kernel<<<dim3(16, 32), dim3(256), 0, stream>>>(
            qb, kb, vb, yb, yb, nullptr, nullptr, 0);
        tcvt_kernel<<<dim3(1024 / 64, 1024 / 64), dim3(256), 0, stream>>>(w_out, woutT, 1024);
    }

    // K3: output projection, 128x64 tiles (512 blocks, 2/CU) -> d_out fp32
    gemm_bt_kernel<bf16_t, 1, 64><<<dim3(1024 / 64, 4096 / 128), dim3(256), 0, stream>>>(
        yb, woutT, b_out, out, nullptr, nullptr, nullptr);
}